// Round 19
// baseline (286.169 us; speedup 1.0000x reference)
//
#include <hip/hip_runtime.h>
#include <hip/hip_bf16.h>
#include <cstdint>

typedef unsigned short u16;
typedef unsigned int u32;
typedef __bf16 bf16x8 __attribute__((ext_vector_type(8)));
typedef float f32x4 __attribute__((ext_vector_type(4)));
typedef u16 u16x8 __attribute__((ext_vector_type(8)));

#define DEVINL __device__ __forceinline__

typedef __attribute__((address_space(1))) const u32 gbl_u32;
typedef __attribute__((address_space(3))) u32 lds_u32;

DEVINL void llds16(const void* g, void* l) {
  __builtin_amdgcn_global_load_lds((gbl_u32*)g, (lds_u32*)l, 16, 0, 0);
}

DEVINL u16 f2bf(float f) {
  union { float f; u32 i; } x; x.f = f;
  u32 r = x.i + 0x7FFFu + ((x.i >> 16) & 1u);
  return (u16)(r >> 16);
}

DEVINL float fast_tanh(float x) {
  x = fminf(10.f, fmaxf(-10.f, x));
  float e = __expf(2.f * x);
  return (e - 1.f) / (e + 1.f);
}

DEVINL bf16x8 cvt8(const float4& a, const float4& b) {
  bf16x8 r;
  r[0] = (__bf16)a.x; r[1] = (__bf16)a.y; r[2] = (__bf16)a.z; r[3] = (__bf16)a.w;
  r[4] = (__bf16)b.x; r[5] = (__bf16)b.y; r[6] = (__bf16)b.z; r[7] = (__bf16)b.w;
  return r;
}

// ---------------------------------------------------------------------------
// Fused prep: all 5 weight tilings in one kernel.
// ---------------------------------------------------------------------------
DEVINL void tile64_one(const float* src, int srcld, int koff, u16* dst, int id) {
  int n = id >> 7, k8 = id & 127;
  int kb = k8 >> 3, h = k8 & 7;
  int u = h * 256 + ((n & 255) ^ (h << 1));
  const float* s = src + (size_t)n * srcld + koff + k8 * 8;
  *(bf16x8*)(dst + ((size_t)((n >> 8) * 16 + kb) * 2048 + u) * 8) =
      cvt8(*(const float4*)s, *(const float4*)(s + 4));
}

__global__ __launch_bounds__(256) void prep_weights(
    const float* __restrict__ W_in, const float* __restrict__ W_in2,
    const float* __restrict__ W_out, const float* __restrict__ W_fc,
    u16* __restrict__ wibf, u16* __restrict__ wi2bf, u16* __restrict__ wobf,
    u16* __restrict__ wf0, u16* __restrict__ wf1) {
  int id = blockIdx.x * 256 + threadIdx.x;
  if (id < 131072) {
    tile64_one(W_in, 1024, 0, wibf, id);
  } else if (id < 262144) {
    tile64_one(W_in2, 1024, 0, wi2bf, id - 131072);
  } else if (id < 327680) {
    int lid = id - 262144;
    int n = lid >> 7, k8 = lid & 127;
    int kb = k8 >> 2, h = k8 & 3;
    int u = h * 128 + ((n & 127) ^ (h << 1));
    const float* s = W_out + (size_t)n * 1024 + k8 * 8;
    *(bf16x8*)(wobf + ((size_t)((n >> 7) * 32 + kb) * 512 + u) * 8) =
        cvt8(*(const float4*)s, *(const float4*)(s + 4));
  } else if (id < 458752) {
    tile64_one(W_fc, 2048, 0, wf0, id - 327680);
  } else if (id < 589824) {
    tile64_one(W_fc, 2048, 1024, wf1, id - 458752);
  }
}

// ---------------------------------------------------------------------------
// Fused activation convert: ctx then query, natural layout bf16.
// ---------------------------------------------------------------------------
__global__ __launch_bounds__(256) void cvt_acts(const float* __restrict__ ctx,
                                                const float* __restrict__ query,
                                                u16* __restrict__ cbf,
                                                u16* __restrict__ qbf) {
  int i = blockIdx.x * 256 + threadIdx.x;
  const float* s;
  u16* d;
  if (i < 2097152) {
    s = ctx + (size_t)i * 8;
    d = cbf + (size_t)i * 8;
  } else {
    int j = i - 2097152;
    s = query + (size_t)j * 8;
    d = qbf + (size_t)j * 8;
  }
  *(bf16x8*)d = cvt8(*(const float4*)s, *(const float4*)(s + 4));
}

// ---------------------------------------------------------------------------
// gemm_nt10: 256x256, BK=64, 8 waves (2Mx4N) — R14 schedule + R14
// XCD-bijective swizzle. R19: manual lgkmcnt(0)+sched_barrier(0) removed
// from phase bodies — compiler inserts fine-grained lgkm waits per operand
// (m97/G7 evidence); WAR safety rests on vmcnt guards + distinct buffers.
// ---------------------------------------------------------------------------
template <int NSEG, bool OUT_BF16, bool TANH>
__global__ __launch_bounds__(512) void gemm_nt10(
    const u16* __restrict__ A0, const u16* __restrict__ A1,
    const u16* __restrict__ Bt0, const u16* __restrict__ Bt1,
    const float* __restrict__ bias0, const float* __restrict__ bias1,
    void* __restrict__ Cout, int ldc) {
  __shared__ u16 As[3][16384];
  __shared__ u16 Bs[2][16384];
  const int tid = threadIdx.x, lane = tid & 63, w = tid >> 6;
  const int wr = w >> 2, wc = w & 3;

  // XCD-bijective swizzle (total % 8 == 0)
  const int NX = gridDim.x;
  const int total = NX * gridDim.y;
  const int flat = blockIdx.y * NX + blockIdx.x;
  const int wid = (flat & 7) * (total >> 3) + (flat >> 3);
  const int nb = wid % NX;
  const int n0 = nb * 256, m0 = (wid / NX) * 256;

  f32x4 acc[8][4];
#pragma unroll
  for (int i = 0; i < 8; ++i)
#pragma unroll
    for (int j = 0; j < 4; ++j) acc[i][j] = (f32x4)0.f;

  u32 asrc[4], bofs[4];
#pragma unroll
  for (int r = 0; r < 4; ++r) {
    int u = r * 512 + w * 64 + lane;
    int row = u >> 3, oct = (u & 7) ^ (row & 7);
    asrc[r] = (u32)(m0 + row) * 1024u + (u32)(oct * 8);
    bofs[r] = (u32)u * 8u;
  }

  const int NT = NSEG * 16;

  auto stageA = [&](int t) {
    const int seg = (NSEG == 2 && t >= 16) ? 1 : 0;
    const int kb = t - (seg << 4);
    const u16* Ap = seg ? A1 : A0;
    const u32 k0 = (u32)(kb << 6);
    u16* dst = As[t % 3];
#pragma unroll
    for (int q = 0; q < 4; ++q)
      llds16(Ap + (size_t)(asrc[q] + k0), dst + (q * 512 + w * 64) * 8);
  };
  auto stageA2 = [&](int t, int rp) {
    const int seg = (NSEG == 2 && t >= 16) ? 1 : 0;
    const int kb = t - (seg << 4);
    const u16* Ap = seg ? A1 : A0;
    const u32 k0 = (u32)(kb << 6);
    u16* dst = As[t % 3];
#pragma unroll
    for (int r = 0; r < 2; ++r) {
      const int q = rp * 2 + r;
      llds16(Ap + (size_t)(asrc[q] + k0), dst + (q * 512 + w * 64) * 8);
    }
  };
  auto stageB = [&](int t) {
    const int seg = (NSEG == 2 && t >= 16) ? 1 : 0;
    const int kb = t - (seg << 4);
    const u16* Bt = (seg ? Bt1 : Bt0) + ((size_t)(nb * 16 + kb) << 14);
    u16* dst = Bs[t & 1];
#pragma unroll
    for (int q = 0; q < 4; ++q)
      llds16(Bt + (size_t)bofs[q], dst + (q * 512 + w * 64) * 8);
  };
  auto stageB2 = [&](int t, int rp) {
    const int seg = (NSEG == 2 && t >= 16) ? 1 : 0;
    const int kb = t - (seg << 4);
    const u16* Bt = (seg ? Bt1 : Bt0) + ((size_t)(nb * 16 + kb) << 14);
    u16* dst = Bs[t & 1];
#pragma unroll
    for (int r = 0; r < 2; ++r) {
      const int q = rp * 2 + r;
      llds16(Bt + (size_t)bofs[q], dst + (q * 512 + w * 64) * 8);
    }
  };

  stageA(0);
  stageB(0);
  if (NT > 1) stageA(1);
  asm volatile("s_waitcnt vmcnt(6)" ::: "memory");
  __builtin_amdgcn_s_barrier();

  const int rl = lane & 15;
  for (int t = 0; t < NT; ++t) {
    const int ab = t % 3, bb = t & 1;
    const bool preB = (t + 1 < NT);
    const bool preA = (t + 2 < NT);
    bf16x8 af[8];

    {  // P0
      const int h = lane >> 4;
      const int jA = h ^ (rl & 7);
#pragma unroll
      for (int i = 0; i < 8; ++i)
        af[i] = *(const bf16x8*)&As[ab][((wr * 128 + i * 16 + rl) * 8 + jA) * 8];
      bf16x8 b0 = *(const bf16x8*)&Bs[bb][(h * 256 + ((wc * 64 + 0 + rl) ^ (h << 1))) * 8];
      bf16x8 b1 = *(const bf16x8*)&Bs[bb][(h * 256 + ((wc * 64 + 16 + rl) ^ (h << 1))) * 8];
      if (preB) stageB2(t + 1, 0);
      __builtin_amdgcn_s_barrier();
      __builtin_amdgcn_s_setprio(1);
#pragma unroll
      for (int i = 0; i < 8; ++i) {
        acc[i][0] = __builtin_amdgcn_mfma_f32_16x16x32_bf16(af[i], b0, acc[i][0], 0, 0, 0);
        acc[i][1] = __builtin_amdgcn_mfma_f32_16x16x32_bf16(af[i], b1, acc[i][1], 0, 0, 0);
      }
      __builtin_amdgcn_s_setprio(0);
    }
    {  // P1
      const int h = lane >> 4;
      bf16x8 b2 = *(const bf16x8*)&Bs[bb][(h * 256 + ((wc * 64 + 32 + rl) ^ (h << 1))) * 8];
      bf16x8 b3 = *(const bf16x8*)&Bs[bb][(h * 256 + ((wc * 64 + 48 + rl) ^ (h << 1))) * 8];
      if (preB) stageB2(t + 1, 1);
      if (preB) asm volatile("s_waitcnt vmcnt(8)" ::: "memory");
      else      asm volatile("s_waitcnt vmcnt(0)" ::: "memory");
      __builtin_amdgcn_s_barrier();
      __builtin_amdgcn_s_setprio(1);
#pragma unroll
      for (int i = 0; i < 8; ++i) {
        acc[i][2] = __builtin_amdgcn_mfma_f32_16x16x32_bf16(af[i], b2, acc[i][2], 0, 0, 0);
        acc[i][3] = __builtin_amdgcn_mfma_f32_16x16x32_bf16(af[i], b3, acc[i][3], 0, 0, 0);
      }
      __builtin_amdgcn_s_setprio(0);
    }
    {  // P2
      const int h = 4 + (lane >> 4);
      const int jA = h ^ (rl & 7);
#pragma unroll
      for (int i = 0; i < 8; ++i)
        af[i] = *(const bf16x8*)&As[ab][((wr * 128 + i * 16 + rl) * 8 + jA) * 8];
      bf16x8 b0 = *(const bf16x8*)&Bs[bb][(h * 256 + ((wc * 64 + 0 + rl) ^ (h << 1))) * 8];
      bf16x8 b1 = *(const bf16x8*)&Bs[bb][(h * 256 + ((wc * 64 + 16 + rl) ^ (h << 1))) * 8];
      if (preA) stageA2(t + 2, 0);
      __builtin_amdgcn_s_barrier();
      __builtin_amdgcn_s_setprio(1);
#pragma unroll
      for (int i = 0; i < 8; ++i) {
        acc[i][0] = __builtin_amdgcn_mfma_f32_16x16x32_bf16(af[i], b0, acc[i][0], 0, 0, 0);
        acc[i][1] = __builtin_amdgcn_mfma_f32_16x16x32_bf16(af[i], b1, acc[i][1], 0, 0, 0);
      }
      __builtin_amdgcn_s_setprio(0);
    }
    {  // P3
      const int h = 4 + (lane >> 4);
      bf16x8 b2 = *(const bf16x8*)&Bs[bb][(h * 256 + ((wc * 64 + 32 + rl) ^ (h << 1))) * 8];
      bf16x8 b3 = *(const bf16x8*)&Bs[bb][(h * 256 + ((wc * 64 + 48 + rl) ^ (h << 1))) * 8];
      if (preA) stageA2(t + 2, 1);
      if (t < NT - 2)       asm volatile("s_waitcnt vmcnt(6)" ::: "memory");
      else if (t == NT - 2) asm volatile("s_waitcnt vmcnt(2)" ::: "memory");
      else                  asm volatile("s_waitcnt vmcnt(0)" ::: "memory");
      __builtin_amdgcn_s_barrier();
      __builtin_amdgcn_s_setprio(1);
#pragma unroll
      for (int i = 0; i < 8; ++i) {
        acc[i][2] = __builtin_amdgcn_mfma_f32_16x16x32_bf16(af[i], b2, acc[i][2], 0, 0, 0);
        acc[i][3] = __builtin_amdgcn_mfma_f32_16x16x32_bf16(af[i], b3, acc[i][3], 0, 0, 0);
      }
      __builtin_amdgcn_s_setprio(0);
    }
  }

  const int rq = lane >> 4;
#pragma unroll
  for (int j = 0; j < 4; ++j) {
    const int gc = n0 + wc * 64 + j * 16 + rl;
    float bia = 0.f;
    if (bias0) bia += bias0[gc];
    if (NSEG == 2 && bias1) bia += bias1[gc];
#pragma unroll
    for (int i = 0; i < 8; ++i) {
#pragma unroll
      for (int r = 0; r < 4; ++r) {
        const int grow = m0 + wr * 128 + i * 16 + rq * 4 + r;
        float v = acc[i][j][r] + bia;
        if (TANH) v = fast_tanh(v);
        if (OUT_BF16)
          ((u16*)Cout)[(size_t)grow * ldc + gc] = f2bf(v);
        else
          ((float*)Cout)[(size_t)grow * ldc + gc] = v;
      }
    }
  }
}

// ---------------------------------------------------------------------------
// score_softmax: FUSED K2+K3 + bf16 alpha side-write for K4.
// ---------------------------------------------------------------------------
__global__ __launch_bounds__(256) void score_softmax(
    const u16* __restrict__ A, const u16* __restrict__ Bt,
    float* __restrict__ alpha, u16* __restrict__ albf) {
  __shared__ u16 As[2][2048];
  __shared__ u16 Bs[2][16384];
  const int tid = threadIdx.x, lane = tid & 63, w = tid >> 6;
  const int m0 = blockIdx.x * 64;
  const int rl = lane & 15, rq = lane >> 4;

  f32x4 acc[32];
#pragma unroll
  for (int j = 0; j < 32; ++j) acc[j] = (f32x4)0.f;

  const int arow = tid >> 2;
  const u32 asrc = (u32)(m0 + arow) * 1024u + (u32)(((tid & 3) ^ (arow & 3)) * 8);

  auto stage = [&](int kb, int buf) {
    llds16(A + (size_t)(asrc + (u32)(kb << 5)), &As[buf][tid * 8]);
#pragma unroll
    for (int p = 0; p < 8; ++p) {
      int u = p * 256 + tid;
      int s = u >> 9;
      llds16(Bt + ((size_t)((s * 32 + kb) * 512 + (u & 511))) * 8,
             &Bs[buf][(p * 256 + w * 64) * 8]);
    }
  };
  auto compute = [&](int buf) {
    const int h = rq;
    const int row = w * 16 + rl;
    bf16x8 af = *(const bf16x8*)&As[buf][(row * 4 + (h ^ (row & 3))) * 8];
#pragma unroll
    for (int j = 0; j < 32; ++j) {
      const int nl = 16 * (j & 7) + rl;
      const int s = j >> 3;
      bf16x8 bv = *(const bf16x8*)&Bs[buf][(s * 512 + h * 128 + (nl ^ (h << 1))) * 8];
      acc[j] = __builtin_amdgcn_mfma_f32_16x16x32_bf16(af, bv, acc[j], 0, 0, 0);
    }
  };

  stage(0, 0);
  __syncthreads();
  for (int t = 0; t < 32; ++t) {
    const int c = t & 1;
    if (t + 1 < 32) stage(t + 1, c ^ 1);
    compute(c);
    __syncthreads();
  }

  float inv[4];
#pragma unroll
  for (int r = 0; r < 4; ++r) {
    float m = acc[0][r];
#pragma unroll
    for (int j = 1; j < 32; ++j) m = fmaxf(m, acc[j][r]);
#pragma unroll
    for (int mask = 1; mask < 16; mask <<= 1)
      m = fmaxf(m, __shfl_xor(m, mask, 64));
    float s = 0.f;
#pragma unroll
    for (int j = 0; j < 32; ++j) {
      acc[j][r] = __expf(acc[j][r] - m);
      s += acc[j][r];
    }
#pragma unroll
    for (int mask = 1; mask < 16; mask <<= 1) s += __shfl_xor(s, mask, 64);
    inv[r] = 1.f / s;
  }

  const int growb = m0 + w * 16 + rq * 4;
#pragma unroll
  for (int j = 0; j < 32; ++j) {
    const int gc = j * 16 + rl;
#pragma unroll
    for (int r = 0; r < 4; ++r) {
      float v = acc[j][r] * inv[r];
      alpha[(size_t)(growb + r) * 512 + gc] = v;
      albf[(size_t)(growb + r) * 512 + gc] = f2bf(v);
    }
  }
}

// ---------------------------------------------------------------------------
// NN GEMM (per batch): mix[l,d] = sum_w albf[l,w]*ctx_bf[w,d]; K=512.
// ---------------------------------------------------------------------------
__global__ __launch_bounds__(256) void gemm_nn4(
    const u16* __restrict__ albf, const u16* __restrict__ ctxb,
    u16* __restrict__ mix) {
  __shared__ u16 As[2][4096];
  __shared__ u16 Bs[2][4096];
  const int tid = threadIdx.x, lane = tid & 63, w = tid >> 6;
  const int wr = w >> 1, wc = w & 1;
  const int b = blockIdx.z;
  const int n0 = blockIdx.x * 128, m0 = blockIdx.y * 128;
  const int h = lane >> 4, rlx = (lane & 15) ^ (h << 1);
  const u16* A = albf + (size_t)b * 262144;
  u16* C = mix + (size_t)b * 524288;

  f32x4 acc[4][4];
#pragma unroll
  for (int i = 0; i < 4; ++i)
#pragma unroll
    for (int j = 0; j < 4; ++j) acc[i][j] = (f32x4)0.f;

  const int row0 = tid >> 2, cb = tid & 3, row1 = 64 + row0;
  const int unit0 = cb * 128 + (row0 ^ (cb << 1));
  const int unit1 = cb * 128 + (row1 ^ (cb << 1));
  const int kl = tid & 31, ng = tid >> 5;
  const int hb = kl >> 3, kp = kl & 7;

  u16x8 ar[2];
  u16x8 ub[2];

  auto stage = [&](int t) {
    const int k0 = t << 5;
    ar[0] = *(const u16x8*)(A + (size_t)(m0 + row0) * 512 + k0 + cb * 8);
    ar[1] = *(const u16x8*)(A + (size_t)(m0 + row1) * 512 + k0 + cb * 8);
    const u16* Cb = ctxb + (size_t)b * 524288 + (size_t)(k0 + kl) * 1024 +
                    n0 + ng * 16;
    ub[0] = *(const u16x8*)Cb; ub[1] = *(const u16x8*)(Cb + 8);
  };
  auto stage_fin = [&](int buf) {
    *(u16x8*)&As[buf][unit0 * 8] = ar[0];
    *(u16x8*)&As[buf][unit1 * 8] = ar[1];
#pragma unroll
    for (int j = 0; j < 16; ++j) {
      int n = ng * 16 + j;
      Bs[buf][(hb * 128 + (n ^ (hb << 1))) * 8 + kp] =
          (j < 8) ? ub[0][j] : ub[1][j - 8];
    }
  };
  auto compute = [&](int buf) {
    bf16x8 af[4], bfv[4];
#pragma unroll
    for (int i = 0; i < 4; ++i)
      af[i] = *(const bf16x8*)&As[buf][(h * 128 + wr * 64 + i * 16 + rlx) * 8];
#pragma unroll
    for (int j = 0; j < 4; ++j)
      bfv[j] = *(const bf16x8*)&Bs[buf][(h * 128 + wc * 64 + j * 16 + rlx) * 8];
#pragma unroll
    for (int i = 0; i < 4; ++i)
#pragma unroll
      for (int j = 0; j < 4; ++j)
        acc[i][j] =
            __builtin_amdgcn_mfma_f32_16x16x32_bf16(af[i], bfv[j], acc[i][j], 0, 0, 0);
  };

  stage(0);
  stage_fin(0);
  __syncthreads();
  for (int t = 0; t < 16; ++t) {
    const int cb_ = t & 1;
    if (t + 1 < 16) stage(t + 1);
    compute(cb_);
    if (t + 1 < 16) stage_fin(cb_ ^ 1);
    __syncthreads();
  }

  const int rl = lane & 15, rq = lane >> 4;
#pragma unroll
  for (int j = 0; j < 4; ++j) {
    const int gc = n0 + wc * 64 + j * 16 + rl;
#pragma unroll
    for (int i = 0; i < 4; ++i) {
#pragma unroll
      for (int r = 0; r < 4; ++r) {
        const int grow = m0 + wr * 64 + i * 16 + rq * 4 + r;
        C[(size_t)grow * 1024 + gc] = f2bf(acc[i][j][r]);
      }
    }
  }
}

// ---------------------------------------------------------------------------
extern "C" void kernel_launch(void* const* d_in, const int* in_sizes, int n_in,
                              void* d_out, int out_size, void* d_ws, size_t ws_size,
                              hipStream_t stream) {
  const float* query = (const float*)d_in[0];  // [32,512,1024] f32
  const float* ctx   = (const float*)d_in[1];  // [32,512,1024]
  const float* W_in  = (const float*)d_in[2];  // [1024,1024]
  const float* b_in  = (const float*)d_in[3];  // [1024]
  const float* W_in2 = (const float*)d_in[4];  // [1024,1024]
  const float* b_in2 = (const float*)d_in[5];  // [1024]
  const float* W_out = (const float*)d_in[6];  // [512,1024]
  const float* W_fc  = (const float*)d_in[7];  // [1024,2048]
  const float* b_fc  = (const float*)d_in[8];  // [1024]

  float* out   = (float*)d_out;               // [32*512*1024] f32
  float* alpha = (float*)d_out + 16777216;    // [32*512*512] f32

  // ws: [weights 9MB][t/mix 33.5MB][cbf 33.5MB][qbf/albf 33.5MB]
  u16* wibf_t  = (u16*)d_ws;                 // 1048576 (tile64 layout)
  u16* wi2bf_t = wibf_t + 1048576;           // 1048576
  u16* wobf_t  = wibf_t + 2097152;           // 524288  (tileb layout)
  u16* wf0_t   = wibf_t + 2621440;           // 1048576
  u16* wf1_t   = wibf_t + 3670016;           // 1048576
  u16* t_ws    = (u16*)((char*)d_ws + 9437184);
  u16* cbf     = (u16*)((char*)d_ws + 42991616);
  u16* qbf     = (u16*)((char*)d_ws + 76546048);
  u16* albf    = qbf;  // qbf dead after K1; alpha_bf16 [32*512*512]

  dim3 blk(256, 1, 1);
  dim3 blk5(512, 1, 1);

  // K0a: all weight tilings in one launch
  prep_weights<<<dim3(2304), blk, 0, stream>>>(W_in, W_in2, W_out, W_fc,
                                               wibf_t, wi2bf_t, wobf_t, wf0_t,
                                               wf1_t);
  // K0b: ctx + query f32->bf16 in one launch
  cvt_acts<<<dim3(16384), blk, 0, stream>>>(ctx, query, cbf, qbf);

  // K1: t = tanh(query@W_in^T + ctx@W_in2^T + b_in + b_in2) -> bf16
  gemm_nt10<2, true, true><<<dim3(4, 64), blk5, 0, stream>>>(
      qbf, cbf, wibf_t, wi2bf_t, b_in, b_in2, t_ws, 1024);

  // K2+K3 fused: alpha = softmax(t @ W_out^T) -> f32 d_out + bf16 ws
  score_softmax<<<dim3(256), blk, 0, stream>>>(t_ws, wobf_t, alpha, albf);

  // K4: mix = albf @ ctx -> bf16 (t region; t dead after K2)
  gemm_nn4<<<dim3(8, 4, 32), blk, 0, stream>>>(albf, cbf, t_ws);

  // K5: out = mix@W_fc[:, :1024]^T + ctx@W_fc[:, 1024:]^T + b_fc -> f32
  gemm_nt10<2, false, false><<<dim3(4, 64), blk5, 0, stream>>>(
      t_ws, cbf, wf0_t, wf1_t, b_fc, nullptr, out, 1024);
}

// Round 20
// 277.528 us; speedup vs baseline: 1.0311x; 1.0311x over previous
//
#include <hip/hip_runtime.h>
#include <hip/hip_bf16.h>
#include <cstdint>

typedef unsigned short u16;
typedef unsigned int u32;
typedef __bf16 bf16x8 __attribute__((ext_vector_type(8)));
typedef float f32x4 __attribute__((ext_vector_type(4)));
typedef u16 u16x8 __attribute__((ext_vector_type(8)));

#define DEVINL __device__ __forceinline__

typedef __attribute__((address_space(1))) const u32 gbl_u32;
typedef __attribute__((address_space(3))) u32 lds_u32;

DEVINL void llds16(const void* g, void* l) {
  __builtin_amdgcn_global_load_lds((gbl_u32*)g, (lds_u32*)l, 16, 0, 0);
}

DEVINL u16 f2bf(float f) {
  union { float f; u32 i; } x; x.f = f;
  u32 r = x.i + 0x7FFFu + ((x.i >> 16) & 1u);
  return (u16)(r >> 16);
}

DEVINL float fast_tanh(float x) {
  x = fminf(10.f, fmaxf(-10.f, x));
  float e = __expf(2.f * x);
  return (e - 1.f) / (e + 1.f);
}

DEVINL bf16x8 cvt8(const float4& a, const float4& b) {
  bf16x8 r;
  r[0] = (__bf16)a.x; r[1] = (__bf16)a.y; r[2] = (__bf16)a.z; r[3] = (__bf16)a.w;
  r[4] = (__bf16)b.x; r[5] = (__bf16)b.y; r[6] = (__bf16)b.z; r[7] = (__bf16)b.w;
  return r;
}

// ---------------------------------------------------------------------------
// Fused prep: all 5 weight tilings in one kernel.
// ---------------------------------------------------------------------------
DEVINL void tile64_one(const float* src, int srcld, int koff, u16* dst, int id) {
  int n = id >> 7, k8 = id & 127;
  int kb = k8 >> 3, h = k8 & 7;
  int u = h * 256 + ((n & 255) ^ (h << 1));
  const float* s = src + (size_t)n * srcld + koff + k8 * 8;
  *(bf16x8*)(dst + ((size_t)((n >> 8) * 16 + kb) * 2048 + u) * 8) =
      cvt8(*(const float4*)s, *(const float4*)(s + 4));
}

__global__ __launch_bounds__(256) void prep_weights(
    const float* __restrict__ W_in, const float* __restrict__ W_in2,
    const float* __restrict__ W_out, const float* __restrict__ W_fc,
    u16* __restrict__ wibf, u16* __restrict__ wi2bf, u16* __restrict__ wobf,
    u16* __restrict__ wf0, u16* __restrict__ wf1) {
  int id = blockIdx.x * 256 + threadIdx.x;
  if (id < 131072) {
    tile64_one(W_in, 1024, 0, wibf, id);
  } else if (id < 262144) {
    tile64_one(W_in2, 1024, 0, wi2bf, id - 131072);
  } else if (id < 327680) {
    int lid = id - 262144;
    int n = lid >> 7, k8 = lid & 127;
    int kb = k8 >> 2, h = k8 & 3;
    int u = h * 128 + ((n & 127) ^ (h << 1));
    const float* s = W_out + (size_t)n * 1024 + k8 * 8;
    *(bf16x8*)(wobf + ((size_t)((n >> 7) * 32 + kb) * 512 + u) * 8) =
        cvt8(*(const float4*)s, *(const float4*)(s + 4));
  } else if (id < 458752) {
    tile64_one(W_fc, 2048, 0, wf0, id - 327680);
  } else if (id < 589824) {
    tile64_one(W_fc, 2048, 1024, wf1, id - 458752);
  }
}

// ---------------------------------------------------------------------------
// Fused activation convert: ctx then query, natural layout bf16.
// ---------------------------------------------------------------------------
__global__ __launch_bounds__(256) void cvt_acts(const float* __restrict__ ctx,
                                                const float* __restrict__ query,
                                                u16* __restrict__ cbf,
                                                u16* __restrict__ qbf) {
  int i = blockIdx.x * 256 + threadIdx.x;
  const float* s;
  u16* d;
  if (i < 2097152) {
    s = ctx + (size_t)i * 8;
    d = cbf + (size_t)i * 8;
  } else {
    int j = i - 2097152;
    s = query + (size_t)j * 8;
    d = qbf + (size_t)j * 8;
  }
  *(bf16x8*)d = cvt8(*(const float4*)s, *(const float4*)(s + 4));
}

// ---------------------------------------------------------------------------
// gemm_nt10: 256x256, BK=64, 8 waves (2Mx4N) — R14 schedule + R14
// XCD-bijective swizzle (empirical best configuration, R18 = 278.6 us).
// ---------------------------------------------------------------------------
template <int NSEG, bool OUT_BF16, bool TANH>
__global__ __launch_bounds__(512) void gemm_nt10(
    const u16* __restrict__ A0, const u16* __restrict__ A1,
    const u16* __restrict__ Bt0, const u16* __restrict__ Bt1,
    const float* __restrict__ bias0, const float* __restrict__ bias1,
    void* __restrict__ Cout, int ldc) {
  __shared__ u16 As[3][16384];
  __shared__ u16 Bs[2][16384];
  const int tid = threadIdx.x, lane = tid & 63, w = tid >> 6;
  const int wr = w >> 2, wc = w & 3;

  // XCD-bijective swizzle (total % 8 == 0)
  const int NX = gridDim.x;
  const int total = NX * gridDim.y;
  const int flat = blockIdx.y * NX + blockIdx.x;
  const int wid = (flat & 7) * (total >> 3) + (flat >> 3);
  const int nb = wid % NX;
  const int n0 = nb * 256, m0 = (wid / NX) * 256;

  f32x4 acc[8][4];
#pragma unroll
  for (int i = 0; i < 8; ++i)
#pragma unroll
    for (int j = 0; j < 4; ++j) acc[i][j] = (f32x4)0.f;

  u32 asrc[4], bofs[4];
#pragma unroll
  for (int r = 0; r < 4; ++r) {
    int u = r * 512 + w * 64 + lane;
    int row = u >> 3, oct = (u & 7) ^ (row & 7);
    asrc[r] = (u32)(m0 + row) * 1024u + (u32)(oct * 8);
    bofs[r] = (u32)u * 8u;
  }

  const int NT = NSEG * 16;

  auto stageA = [&](int t) {
    const int seg = (NSEG == 2 && t >= 16) ? 1 : 0;
    const int kb = t - (seg << 4);
    const u16* Ap = seg ? A1 : A0;
    const u32 k0 = (u32)(kb << 6);
    u16* dst = As[t % 3];
#pragma unroll
    for (int q = 0; q < 4; ++q)
      llds16(Ap + (size_t)(asrc[q] + k0), dst + (q * 512 + w * 64) * 8);
  };
  auto stageA2 = [&](int t, int rp) {
    const int seg = (NSEG == 2 && t >= 16) ? 1 : 0;
    const int kb = t - (seg << 4);
    const u16* Ap = seg ? A1 : A0;
    const u32 k0 = (u32)(kb << 6);
    u16* dst = As[t % 3];
#pragma unroll
    for (int r = 0; r < 2; ++r) {
      const int q = rp * 2 + r;
      llds16(Ap + (size_t)(asrc[q] + k0), dst + (q * 512 + w * 64) * 8);
    }
  };
  auto stageB = [&](int t) {
    const int seg = (NSEG == 2 && t >= 16) ? 1 : 0;
    const int kb = t - (seg << 4);
    const u16* Bt = (seg ? Bt1 : Bt0) + ((size_t)(nb * 16 + kb) << 14);
    u16* dst = Bs[t & 1];
#pragma unroll
    for (int q = 0; q < 4; ++q)
      llds16(Bt + (size_t)bofs[q], dst + (q * 512 + w * 64) * 8);
  };
  auto stageB2 = [&](int t, int rp) {
    const int seg = (NSEG == 2 && t >= 16) ? 1 : 0;
    const int kb = t - (seg << 4);
    const u16* Bt = (seg ? Bt1 : Bt0) + ((size_t)(nb * 16 + kb) << 14);
    u16* dst = Bs[t & 1];
#pragma unroll
    for (int r = 0; r < 2; ++r) {
      const int q = rp * 2 + r;
      llds16(Bt + (size_t)bofs[q], dst + (q * 512 + w * 64) * 8);
    }
  };

  stageA(0);
  stageB(0);
  if (NT > 1) stageA(1);
  asm volatile("s_waitcnt vmcnt(6)" ::: "memory");
  __builtin_amdgcn_s_barrier();

  const int rl = lane & 15;
  for (int t = 0; t < NT; ++t) {
    const int ab = t % 3, bb = t & 1;
    const bool preB = (t + 1 < NT);
    const bool preA = (t + 2 < NT);
    bf16x8 af[8];

    {  // P0
      const int h = lane >> 4;
      const int jA = h ^ (rl & 7);
#pragma unroll
      for (int i = 0; i < 8; ++i)
        af[i] = *(const bf16x8*)&As[ab][((wr * 128 + i * 16 + rl) * 8 + jA) * 8];
      bf16x8 b0 = *(const bf16x8*)&Bs[bb][(h * 256 + ((wc * 64 + 0 + rl) ^ (h << 1))) * 8];
      bf16x8 b1 = *(const bf16x8*)&Bs[bb][(h * 256 + ((wc * 64 + 16 + rl) ^ (h << 1))) * 8];
      if (preB) stageB2(t + 1, 0);
      __builtin_amdgcn_s_barrier();
      asm volatile("s_waitcnt lgkmcnt(0)" ::: "memory");
      __builtin_amdgcn_sched_barrier(0);
      __builtin_amdgcn_s_setprio(1);
#pragma unroll
      for (int i = 0; i < 8; ++i) {
        acc[i][0] = __builtin_amdgcn_mfma_f32_16x16x32_bf16(af[i], b0, acc[i][0], 0, 0, 0);
        acc[i][1] = __builtin_amdgcn_mfma_f32_16x16x32_bf16(af[i], b1, acc[i][1], 0, 0, 0);
      }
      __builtin_amdgcn_s_setprio(0);
    }
    {  // P1
      const int h = lane >> 4;
      bf16x8 b2 = *(const bf16x8*)&Bs[bb][(h * 256 + ((wc * 64 + 32 + rl) ^ (h << 1))) * 8];
      bf16x8 b3 = *(const bf16x8*)&Bs[bb][(h * 256 + ((wc * 64 + 48 + rl) ^ (h << 1))) * 8];
      if (preB) stageB2(t + 1, 1);
      if (preB) asm volatile("s_waitcnt vmcnt(8)" ::: "memory");
      else      asm volatile("s_waitcnt vmcnt(0)" ::: "memory");
      __builtin_amdgcn_s_barrier();
      asm volatile("s_waitcnt lgkmcnt(0)" ::: "memory");
      __builtin_amdgcn_sched_barrier(0);
      __builtin_amdgcn_s_setprio(1);
#pragma unroll
      for (int i = 0; i < 8; ++i) {
        acc[i][2] = __builtin_amdgcn_mfma_f32_16x16x32_bf16(af[i], b2, acc[i][2], 0, 0, 0);
        acc[i][3] = __builtin_amdgcn_mfma_f32_16x16x32_bf16(af[i], b3, acc[i][3], 0, 0, 0);
      }
      __builtin_amdgcn_s_setprio(0);
    }
    {  // P2
      const int h = 4 + (lane >> 4);
      const int jA = h ^ (rl & 7);
#pragma unroll
      for (int i = 0; i < 8; ++i)
        af[i] = *(const bf16x8*)&As[ab][((wr * 128 + i * 16 + rl) * 8 + jA) * 8];
      bf16x8 b0 = *(const bf16x8*)&Bs[bb][(h * 256 + ((wc * 64 + 0 + rl) ^ (h << 1))) * 8];
      bf16x8 b1 = *(const bf16x8*)&Bs[bb][(h * 256 + ((wc * 64 + 16 + rl) ^ (h << 1))) * 8];
      if (preA) stageA2(t + 2, 0);
      __builtin_amdgcn_s_barrier();
      asm volatile("s_waitcnt lgkmcnt(0)" ::: "memory");
      __builtin_amdgcn_sched_barrier(0);
      __builtin_amdgcn_s_setprio(1);
#pragma unroll
      for (int i = 0; i < 8; ++i) {
        acc[i][0] = __builtin_amdgcn_mfma_f32_16x16x32_bf16(af[i], b0, acc[i][0], 0, 0, 0);
        acc[i][1] = __builtin_amdgcn_mfma_f32_16x16x32_bf16(af[i], b1, acc[i][1], 0, 0, 0);
      }
      __builtin_amdgcn_s_setprio(0);
    }
    {  // P3
      const int h = 4 + (lane >> 4);
      bf16x8 b2 = *(const bf16x8*)&Bs[bb][(h * 256 + ((wc * 64 + 32 + rl) ^ (h << 1))) * 8];
      bf16x8 b3 = *(const bf16x8*)&Bs[bb][(h * 256 + ((wc * 64 + 48 + rl) ^ (h << 1))) * 8];
      if (preA) stageA2(t + 2, 1);
      if (t < NT - 2)       asm volatile("s_waitcnt vmcnt(6)" ::: "memory");
      else if (t == NT - 2) asm volatile("s_waitcnt vmcnt(2)" ::: "memory");
      else                  asm volatile("s_waitcnt vmcnt(0)" ::: "memory");
      __builtin_amdgcn_s_barrier();
      asm volatile("s_waitcnt lgkmcnt(0)" ::: "memory");
      __builtin_amdgcn_sched_barrier(0);
      __builtin_amdgcn_s_setprio(1);
#pragma unroll
      for (int i = 0; i < 8; ++i) {
        acc[i][2] = __builtin_amdgcn_mfma_f32_16x16x32_bf16(af[i], b2, acc[i][2], 0, 0, 0);
        acc[i][3] = __builtin_amdgcn_mfma_f32_16x16x32_bf16(af[i], b3, acc[i][3], 0, 0, 0);
      }
      __builtin_amdgcn_s_setprio(0);
    }
  }

  const int rq = lane >> 4;
#pragma unroll
  for (int j = 0; j < 4; ++j) {
    const int gc = n0 + wc * 64 + j * 16 + rl;
    float bia = 0.f;
    if (bias0) bia += bias0[gc];
    if (NSEG == 2 && bias1) bia += bias1[gc];
#pragma unroll
    for (int i = 0; i < 8; ++i) {
#pragma unroll
      for (int r = 0; r < 4; ++r) {
        const int grow = m0 + wr * 128 + i * 16 + rq * 4 + r;
        float v = acc[i][j][r] + bia;
        if (TANH) v = fast_tanh(v);
        if (OUT_BF16)
          ((u16*)Cout)[(size_t)grow * ldc + gc] = f2bf(v);
        else
          ((float*)Cout)[(size_t)grow * ldc + gc] = v;
      }
    }
  }
}

// ---------------------------------------------------------------------------
// score_softmax: FUSED K2+K3 + bf16 alpha side-write for K4.
// ---------------------------------------------------------------------------
__global__ __launch_bounds__(256) void score_softmax(
    const u16* __restrict__ A, const u16* __restrict__ Bt,
    float* __restrict__ alpha, u16* __restrict__ albf) {
  __shared__ u16 As[2][2048];
  __shared__ u16 Bs[2][16384];
  const int tid = threadIdx.x, lane = tid & 63, w = tid >> 6;
  const int m0 = blockIdx.x * 64;
  const int rl = lane & 15, rq = lane >> 4;

  f32x4 acc[32];
#pragma unroll
  for (int j = 0; j < 32; ++j) acc[j] = (f32x4)0.f;

  const int arow = tid >> 2;
  const u32 asrc = (u32)(m0 + arow) * 1024u + (u32)(((tid & 3) ^ (arow & 3)) * 8);

  auto stage = [&](int kb, int buf) {
    llds16(A + (size_t)(asrc + (u32)(kb << 5)), &As[buf][tid * 8]);
#pragma unroll
    for (int p = 0; p < 8; ++p) {
      int u = p * 256 + tid;
      int s = u >> 9;
      llds16(Bt + ((size_t)((s * 32 + kb) * 512 + (u & 511))) * 8,
             &Bs[buf][(p * 256 + w * 64) * 8]);
    }
  };
  auto compute = [&](int buf) {
    const int h = rq;
    const int row = w * 16 + rl;
    bf16x8 af = *(const bf16x8*)&As[buf][(row * 4 + (h ^ (row & 3))) * 8];
#pragma unroll
    for (int j = 0; j < 32; ++j) {
      const int nl = 16 * (j & 7) + rl;
      const int s = j >> 3;
      bf16x8 bv = *(const bf16x8*)&Bs[buf][(s * 512 + h * 128 + (nl ^ (h << 1))) * 8];
      acc[j] = __builtin_amdgcn_mfma_f32_16x16x32_bf16(af, bv, acc[j], 0, 0, 0);
    }
  };

  stage(0, 0);
  __syncthreads();
  for (int t = 0; t < 32; ++t) {
    const int c = t & 1;
    if (t + 1 < 32) stage(t + 1, c ^ 1);
    compute(c);
    __syncthreads();
  }

  float inv[4];
#pragma unroll
  for (int r = 0; r < 4; ++r) {
    float m = acc[0][r];
#pragma unroll
    for (int j = 1; j < 32; ++j) m = fmaxf(m, acc[j][r]);
#pragma unroll
    for (int mask = 1; mask < 16; mask <<= 1)
      m = fmaxf(m, __shfl_xor(m, mask, 64));
    float s = 0.f;
#pragma unroll
    for (int j = 0; j < 32; ++j) {
      acc[j][r] = __expf(acc[j][r] - m);
      s += acc[j][r];
    }
#pragma unroll
    for (int mask = 1; mask < 16; mask <<= 1) s += __shfl_xor(s, mask, 64);
    inv[r] = 1.f / s;
  }

  const int growb = m0 + w * 16 + rq * 4;
#pragma unroll
  for (int j = 0; j < 32; ++j) {
    const int gc = j * 16 + rl;
#pragma unroll
    for (int r = 0; r < 4; ++r) {
      float v = acc[j][r] * inv[r];
      alpha[(size_t)(growb + r) * 512 + gc] = v;
      albf[(size_t)(growb + r) * 512 + gc] = f2bf(v);
    }
  }
}

// ---------------------------------------------------------------------------
// NN GEMM (per batch): mix[l,d] = sum_w albf[l,w]*ctx_bf[w,d]; K=512.
// ---------------------------------------------------------------------------
__global__ __launch_bounds__(256) void gemm_nn4(
    const u16* __restrict__ albf, const u16* __restrict__ ctxb,
    u16* __restrict__ mix) {
  __shared__ u16 As[2][4096];
  __shared__ u16 Bs[2][4096];
  const int tid = threadIdx.x, lane = tid & 63, w = tid >> 6;
  const int wr = w >> 1, wc = w & 1;
  const int b = blockIdx.z;
  const int n0 = blockIdx.x * 128, m0 = blockIdx.y * 128;
  const int h = lane >> 4, rlx = (lane & 15) ^ (h << 1);
  const u16* A = albf + (size_t)b * 262144;
  u16* C = mix + (size_t)b * 524288;

  f32x4 acc[4][4];
#pragma unroll
  for (int i = 0; i < 4; ++i)
#pragma unroll
    for (int j = 0; j < 4; ++j) acc[i][j] = (f32x4)0.f;

  const int row0 = tid >> 2, cb = tid & 3, row1 = 64 + row0;
  const int unit0 = cb * 128 + (row0 ^ (cb << 1));
  const int unit1 = cb * 128 + (row1 ^ (cb << 1));
  const int kl = tid & 31, ng = tid >> 5;
  const int hb = kl >> 3, kp = kl & 7;

  u16x8 ar[2];
  u16x8 ub[2];

  auto stage = [&](int t) {
    const int k0 = t << 5;
    ar[0] = *(const u16x8*)(A + (size_t)(m0 + row0) * 512 + k0 + cb * 8);
    ar[1] = *(const u16x8*)(A + (size_t)(m0 + row1) * 512 + k0 + cb * 8);
    const u16* Cb = ctxb + (size_t)b * 524288 + (size_t)(k0 + kl) * 1024 +
                    n0 + ng * 16;
    ub[0] = *(const u16x8*)Cb; ub[1] = *(const u16x8*)(Cb + 8);
  };
  auto stage_fin = [&](int buf) {
    *(u16x8*)&As[buf][unit0 * 8] = ar[0];
    *(u16x8*)&As[buf][unit1 * 8] = ar[1];
#pragma unroll
    for (int j = 0; j < 16; ++j) {
      int n = ng * 16 + j;
      Bs[buf][(hb * 128 + (n ^ (hb << 1))) * 8 + kp] =
          (j < 8) ? ub[0][j] : ub[1][j - 8];
    }
  };
  auto compute = [&](int buf) {
    bf16x8 af[4], bfv[4];
#pragma unroll
    for (int i = 0; i < 4; ++i)
      af[i] = *(const bf16x8*)&As[buf][(h * 128 + wr * 64 + i * 16 + rlx) * 8];
#pragma unroll
    for (int j = 0; j < 4; ++j)
      bfv[j] = *(const bf16x8*)&Bs[buf][(h * 128 + wc * 64 + j * 16 + rlx) * 8];
#pragma unroll
    for (int i = 0; i < 4; ++i)
#pragma unroll
      for (int j = 0; j < 4; ++j)
        acc[i][j] =
            __builtin_amdgcn_mfma_f32_16x16x32_bf16(af[i], bfv[j], acc[i][j], 0, 0, 0);
  };

  stage(0);
  stage_fin(0);
  __syncthreads();
  for (int t = 0; t < 16; ++t) {
    const int cb_ = t & 1;
    if (t + 1 < 16) stage(t + 1);
    compute(cb_);
    if (t + 1 < 16) stage_fin(cb_ ^ 1);
    __syncthreads();
  }

  const int rl = lane & 15, rq = lane >> 4;
#pragma unroll
  for (int j = 0; j < 4; ++j) {
    const int gc = n0 + wc * 64 + j * 16 + rl;
#pragma unroll
    for (int i = 0; i < 4; ++i) {
#pragma unroll
      for (int r = 0; r < 4; ++r) {
        const int grow = m0 + wr * 64 + i * 16 + rq * 4 + r;
        C[(size_t)grow * 1024 + gc] = f2bf(acc[i][j][r]);
      }
    }
  }
}

// ---------------------------------------------------------------------------
extern "C" void kernel_launch(void* const* d_in, const int* in_sizes, int n_in,
                              void* d_out, int out_size, void* d_ws, size_t ws_size,
                              hipStream_t stream) {
  const float* query = (const float*)d_in[0];  // [32,512,1024] f32
  const float* ctx   = (const float*)d_in[1];  // [32,512,1024]
  const float* W_in  = (const float*)d_in[2];  // [1024,1024]
  const float* b_in  = (const float*)d_in[3];  // [1024]
  const float* W_in2 = (const float*)d_in[4];  // [1024,1024]
  const float* b_in2 = (const float*)d_in[5];  // [1024]
  const float* W_out = (const float*)d_in[6];  // [512,1024]
  const float* W_fc  = (const float*)d_in[7];  // [1024,2048]
  const float* b_fc  = (const float*)d_in[8];  // [1024]

  float* out   = (float*)d_out;               // [32*512*1024] f32
  float* alpha = (float*)d_out + 16777216;    // [32*512*512] f32

  // ws: [weights 9MB][t/mix 33.5MB][cbf 33.5MB][qbf/albf 33.5MB]
  u16* wibf_t  = (u16*)d_ws;                 // 1048576 (tile64 layout)
  u16* wi2bf_t = wibf_t + 1048576;           // 1048576
  u16* wobf_t  = wibf_t + 2097152;           // 524288  (tileb layout)
  u16* wf0_t   = wibf_t + 2621440;           // 1048576
  u16* wf1_t   = wibf_t + 3670016;           // 1048576
  u16* t_ws    = (u16*)((char*)d_ws + 9437184);
  u16* cbf     = (u16*)((char*)d_ws + 42991616);
  u16* qbf     = (u16*)((char*)d_ws + 76546048);
  u16* albf    = qbf;  // qbf dead after K1; alpha_bf16 [32*512*512]

  dim3 blk(256, 1, 1);
  dim3 blk5(512, 1, 1);

  // K0a: all weight tilings in one launch
  prep_weights<<<dim3(2304), blk, 0, stream>>>(W_in, W_in2, W_out, W_fc,
                                               wibf_t, wi2bf_t, wobf_t, wf0_t,
                                               wf1_t);
  // K0b: ctx + query f32->bf16 in one launch
  cvt_acts<<<dim3(16384), blk, 0, stream>>>(ctx, query, cbf, qbf);

  // K1: t = tanh(query@W_in^T + ctx@W_in2^T + b_in + b_in2) -> bf16
  gemm_nt10<2, true, true><<<dim3(4, 64), blk5, 0, stream>>>(
      qbf, cbf, wibf_t, wi2bf_t, b_in, b_in2, t_ws, 1024);

  // K2+K3 fused: alpha = softmax(t @ W_out^T) -> f32 d_out + bf16 ws
  score_softmax<<<dim3(256), blk, 0, stream>>>(t_ws, wobf_t, alpha, albf);

  // K4: mix = albf @ ctx -> bf16 (t region; t dead after K2)
  gemm_nn4<<<dim3(8, 4, 32), blk, 0, stream>>>(albf, cbf, t_ws);

  // K5: out = mix@W_fc[:, :1024]^T + ctx@W_fc[:, 1024:]^T + b_fc -> f32
  gemm_nt10<2, false, false><<<dim3(4, 64), blk5, 0, stream>>>(
      t_ws, cbf, wf0_t, wf1_t, b_fc, nullptr, out, 1024);
}